// Round 4
// baseline (1034.363 us; speedup 1.0000x reference)
//
#include <hip/hip_runtime.h>
#include <hip/hip_bf16.h>
#include <stdint.h>

typedef __bf16 bf16;
typedef __attribute__((ext_vector_type(8))) __bf16 bf16x8;
typedef __attribute__((ext_vector_type(4))) __bf16 bf16x4;
typedef __attribute__((ext_vector_type(4))) float f32x4;

#define B_ 2
#define F_ 128
#define P_ 256
#define H_ 8
#define D_ 64
#define DIM_ 512
#define NROWS (B_*F_*P_)   // 65536

// async global->LDS, 16B per lane. LDS dest must be wave-uniform base + lane*16.
__device__ __forceinline__ void load_lds16(const void* g, void* l) {
  __builtin_amdgcn_global_load_lds(
      (__attribute__((address_space(1))) void*)(uintptr_t)g,
      (__attribute__((address_space(3))) void*)(uint32_t)(uintptr_t)l,
      16, 0, 0);
}

// fp32 -> bf16 cast, 8 elements/thread (n must be a multiple of 8)
__global__ void cvt_f32_bf16(const float* __restrict__ src, bf16* __restrict__ dst, int n)
{
  int i = (blockIdx.x * 256 + threadIdx.x) * 8;
  if (i < n) {
    float4 a = *(const float4*)(src + i);
    float4 b = *(const float4*)(src + i + 4);
    bf16x8 o;
    o[0] = (bf16)a.x; o[1] = (bf16)a.y; o[2] = (bf16)a.z; o[3] = (bf16)a.w;
    o[4] = (bf16)b.x; o[5] = (bf16)b.y; o[6] = (bf16)b.z; o[7] = (bf16)b.w;
    *(bf16x8*)(dst + i) = o;
  }
}

// W_o fp32 [512(he)][512(d)] -> wot bf16 [512(d)][512(he)]
__global__ void transpose_wo(const float* __restrict__ src, bf16* __restrict__ dst)
{
  int idx = blockIdx.x * 256 + threadIdx.x;
  int d = idx & 511, he = idx >> 9;
  dst[(size_t)d * 512 + he] = (bf16)src[(size_t)he * 512 + d];
}

// ---------------------------------------------------------------------------
// gemm: C[M x N] = A[M x K=512] * Bt[N x K]^T + bias[N]
// 256(M) x 128(N) tile, BK=32, 8 waves (4M x 2N), 512 threads, 2 blocks/CU.
//
// Round-4 theory: rounds 1-3 all pinned at MfmaUtil ~28% because the LDS pipe
// (shared by staging WRITES and fragment READS) was the serial resource:
// 88 KB LDS traffic/block-K-tile ~ 786 cyc > MFMA 516 cyc. Fix: B never
// touches LDS. B is 1.5 MB (L2-resident; 4 waves/block share fragments -> L1
// hits); fragments load global->VGPR, register-double-buffered one K-tile
// ahead (~1000 cyc hiding >> ~200 cyc L2 latency). LDS carries A only:
// 48 KB/block-K-tile ~ 429 cyc x2 blocks = 857 < MFMA 1032 -> MFMA-bound.
// LDS ring 3 x 16 KB = 48 KB. Counted vmcnt (A:2 + B:4 per iter -> steady 6).
// k-octet swizzle g(row)=(row>>1)&3 on A only (0 conflicts, verified r1).
// Swapped-operand MFMA -> vectorized epilogue. XCD-chunked block swizzle.
// ---------------------------------------------------------------------------
template <typename OutT, int NTn>            // NTn = N / 128
__global__ __launch_bounds__(512, 4)
void gemm_mn(const bf16* __restrict__ A, const bf16* __restrict__ Bt,
             const float* __restrict__ bias, OutT* __restrict__ C)
{
  constexpr int K = 512;
  constexpr int N = NTn * 128;
  constexpr int NTILES = 16;                 // K / 32
  constexpr int BUF = 8192;                  // elems per ring slot (A only)
  __shared__ __align__(16) bf16 Ls[3 * BUF]; // 48 KiB

  const int t    = threadIdx.x;
  const int lane = t & 63;
  const int l16  = lane & 15;
  const int qd   = lane >> 4;
  const int wave = t >> 6;
  const int wm   = wave >> 1;                // 0..3  (M quarter, 64 rows)
  const int wn   = wave & 1;                 // 0..1  (N half, 64 cols)

  // XCD-aware swizzle: NWG/8 consecutive logical blocks per XCD, N-fast.
  constexpr int NWG = 256 * NTn;
  const int logical = (blockIdx.x & 7) * (NWG / 8) + (blockIdx.x >> 3);
  const int mBase = (logical / NTn) * 256;
  const int nBase = (logical % NTn) * 128;

  // ---- A staging (global_load_lds, 2 x 16B per thread per K-tile) ----
  // chunk c: row c>>2, k-octet (c&3)^g(row), g(row)=(row>>1)&3; c1 = c0+512
  // adds 128 to row, which preserves g(row).
  const int soct = (((t & 3) ^ ((t >> 3) & 3)) << 3);
  const bf16* aP0 = A + (size_t)(mBase + (t >> 2)) * K + soct;
  const bf16* aP1 = aP0 + (size_t)128 * K;

#define STAGE_A(tt) do { bf16* Lb_ = Ls + ((tt) % 3) * BUF; \
    load_lds16(aP0 + (tt) * 32, Lb_ + t * 8); \
    load_lds16(aP1 + (tt) * 32, Lb_ + 4096 + t * 8); } while (0)

  // ---- B fragments: direct global->VGPR (no LDS, no swizzle) ----
  // lane (l16,qd) of frag j reads Bt[nBase + wn*64 + j*16 + l16][k0 + qd*8 ..]
  const bf16* bBase = Bt + (size_t)nBase * K;
  int boff[4];
#pragma unroll
  for (int j = 0; j < 4; ++j)
    boff[j] = (wn * 64 + j * 16 + l16) * K + qd * 8;

  // A fragment read: row = wm*64 + i*16 + l16; g(row) reduces to (l16>>1)&3.
  const int swz    = ((qd ^ ((l16 >> 1) & 3)) << 3);
  const int aRdOff = (wm * 64 + l16) * 32 + swz;

  f32x4 acc[4][4] = {};
  bf16x8 bfr[2][4];                          // register double-buffer for B

#define MF(i, j, av, bv) \
  acc[i][j] = __builtin_amdgcn_mfma_f32_16x16x32_bf16(av, bv, acc[i][j], 0, 0, 0)

  // prologue: B(0) first (so vmcnt(2) drains B0+A0, leaves A1), then A0, A1.
#pragma unroll
  for (int j = 0; j < 4; ++j) bfr[0][j] = *(const bf16x8*)(bBase + boff[j]);
  __builtin_amdgcn_sched_barrier(0);
  STAGE_A(0); STAGE_A(1);
  asm volatile("s_waitcnt vmcnt(2)" ::: "memory");
  __builtin_amdgcn_s_barrier();
  asm volatile("" ::: "memory");

#pragma unroll
  for (int tt = 0; tt < NTILES; ++tt) {
    const int cur = tt & 1, nxt = cur ^ 1;

    // issue next tile's A staging + B fragment loads (used next iteration)
    if (tt + 2 < NTILES) STAGE_A(tt + 2);
    if (tt + 1 < NTILES) {
#pragma unroll
      for (int j = 0; j < 4; ++j)
        bfr[nxt][j] = *(const bf16x8*)(bBase + boff[j] + (tt + 1) * 32);
    }
    // counted wait: A(tt) in LDS + B(tt) in regs; newest {A(tt+2),B(tt+1)}
    // stay in flight. Tail: tt=14 leaves only B(15); tt=15 drains all.
    if      (tt <= NTILES - 3) asm volatile("s_waitcnt vmcnt(6)" ::: "memory");
    else if (tt == NTILES - 2) asm volatile("s_waitcnt vmcnt(4)" ::: "memory");
    else                       asm volatile("s_waitcnt vmcnt(0)" ::: "memory");
    __builtin_amdgcn_s_barrier();            // all waves' A(tt) visible
    asm volatile("" ::: "memory");

    const bf16* Lb = Ls + (tt % 3) * BUF;
    bf16x8 a[4];
#pragma unroll
    for (int i = 0; i < 4; ++i) a[i] = *(const bf16x8*)(Lb + aRdOff + i * 512);

    __builtin_amdgcn_s_setprio(1);
    // swapped operands: lane holds m = i*16+l16 (col), n = j*16+qd*4+r (row)
#pragma unroll
    for (int i = 0; i < 4; ++i)
#pragma unroll
      for (int j = 0; j < 4; ++j) MF(i, j, bfr[cur][j], a[i]);
    __builtin_amdgcn_s_setprio(0);

    asm volatile("s_waitcnt lgkmcnt(0)" ::: "memory");  // my A reads retired
    __builtin_amdgcn_s_barrier();            // buf (tt%3) free for restage
    asm volatile("" ::: "memory");
  }
#undef STAGE_A
#undef MF

  // epilogue: lane holds rows m = mBase+wm*64+i*16+l16,
  // cols n = nBase+wn*64+j*16+qd*4 .. +3 (contiguous) -> vector stores.
#pragma unroll
  for (int j = 0; j < 4; ++j) {
    const int ncol = nBase + wn * 64 + j * 16 + qd * 4;
    const f32x4 bv = *(const f32x4*)(bias + ncol);
#pragma unroll
    for (int i = 0; i < 4; ++i) {
      const size_t off = (size_t)(mBase + wm * 64 + i * 16 + l16) * N + ncol;
      if constexpr (__is_same(OutT, float)) {
        f32x4 o;
#pragma unroll
        for (int r = 0; r < 4; ++r) o[r] = acc[i][j][r] + bv[r];
        *(f32x4*)(C + off) = o;
      } else {
        bf16x4 o;
#pragma unroll
        for (int r = 0; r < 4; ++r) o[r] = (bf16)(acc[i][j][r] + bv[r]);
        *(bf16x4*)(C + off) = o;
      }
    }
  }
}

// ---------------------------------------------------------------------------
// Attention v2: S^T = K·Q^T (C layout: row=key, col=q), softmax in registers,
// O^T = V^T·P^T. Q/K fragments loaded straight from global (b128, no LDS).
// LDS: Vt[64][VS] (V transposed, padded) + Pq[128][136] (wave-private P rows).
// One __syncthreads total. NKT = key tiles of 16 (8 frame / 16 point).
// ---------------------------------------------------------------------------
template <int NKT, int MODE, int VS>
__global__ __launch_bounds__(256, 2)
void attn2(const bf16* __restrict__ qkv, bf16* __restrict__ outp)
{
  __shared__ __align__(16) bf16 Vt[64 * VS];
  __shared__ __align__(16) bf16 Pq[128 * 136];

  const int t    = threadIdx.x;
  const int lane = t & 63;
  const int wave = t >> 6;
  const int l16  = lane & 15;
  const int qd   = lane >> 4;

  const int bid = blockIdx.x;
  int h, q0, rowbase, rstride;
  if (MODE == 0) {
    h = bid & 7;
    int p = (bid >> 3) & (P_ - 1);
    int b = bid >> 11;
    rowbase = b * F_ * P_ + p; rstride = P_; q0 = 0;
  } else {
    int qb = bid & 1;
    h = (bid >> 1) & 7;
    int f = (bid >> 4) & (F_ - 1);
    int b = bid >> 11;
    rowbase = (b * F_ + f) * P_; rstride = 1; q0 = qb * 128;
  }

  // ---- stage V^T into LDS: Vt[e][key], padded stride VS ----
#pragma unroll
  for (int p = 0; p < NKT / 8; ++p) {
    int key = p * 128 + (t >> 1);
    int eh  = (t & 1) * 32;
    const bf16* src = qkv + (size_t)(rowbase + key * rstride) * 1536 + 1024 + h * 64 + eh;
    bf16x8 v[4];
#pragma unroll
    for (int jj = 0; jj < 4; ++jj) v[jj] = *(const bf16x8*)(src + jj * 8);
#pragma unroll
    for (int jj = 0; jj < 4; ++jj)
#pragma unroll
      for (int j = 0; j < 8; ++j)
        Vt[(eh + jj * 8 + j) * VS + key] = v[jj][j];
  }

  // ---- Q fragments (wave owns q columns wave*32..+31), direct global ----
  const int qloc = wave * 32;
  bf16x8 qf[2][2];
#pragma unroll
  for (int qt = 0; qt < 2; ++qt)
#pragma unroll
    for (int ks = 0; ks < 2; ++ks)
      qf[qt][ks] = *(const bf16x8*)(qkv +
          (size_t)(rowbase + (q0 + qloc + qt * 16 + l16) * rstride) * 1536 +
          h * 64 + ks * 32 + qd * 8);

  // ---- S^T = K·Q^T : K fragments direct from global ----
  f32x4 sacc[NKT][2] = {};
#pragma unroll
  for (int tn = 0; tn < NKT; ++tn) {
    const bf16* krow = qkv + (size_t)(rowbase + (tn * 16 + l16) * rstride) * 1536 + 512 + h * 64;
    bf16x8 kf0 = *(const bf16x8*)(krow + qd * 8);
    bf16x8 kf1 = *(const bf16x8*)(krow + 32 + qd * 8);
#pragma unroll
    for (int qt = 0; qt < 2; ++qt) {
      sacc[tn][qt] = __builtin_amdgcn_mfma_f32_16x16x32_bf16(kf0, qf[qt][0], sacc[tn][qt], 0, 0, 0);
      sacc[tn][qt] = __builtin_amdgcn_mfma_f32_16x16x32_bf16(kf1, qf[qt][1], sacc[tn][qt], 0, 0, 0);
    }
  }

  // ---- softmax over keys (rows of S^T): in-lane (tn,r) + shfl over qd ----
#pragma unroll
  for (int qt = 0; qt < 2; ++qt) {
    float m = -3.0e38f;
#pragma unroll
    for (int tn = 0; tn < NKT; ++tn)
#pragma unroll
      for (int r = 0; r < 4; ++r) m = fmaxf(m, sacc[tn][qt][r]);
    m = fmaxf(m, __shfl_xor(m, 16));
    m = fmaxf(m, __shfl_xor(m, 32));
    float s = 0.0f;
#pragma unroll
    for (int tn = 0; tn < NKT; ++tn)
#pragma unroll
      for (int r = 0; r < 4; ++r) {
        float e0 = __expf(sacc[tn][qt][r] - m);
        sacc[tn][qt][r] = e0;
        s += e0;
      }
    s += __shfl_xor(s, 16);
    s += __shfl_xor(s, 32);
    float inv = 1.0f / s;
#pragma unroll
    for (int tn = 0; tn < NKT; ++tn)
#pragma unroll
      for (int r = 0; r < 4; ++r) sacc[tn][qt][r] *= inv;
  }

  // ---- O^T = V^T·P^T, key-halves of 128; Pq rows are wave-private ----
  f32x4 oacc[4][2] = {};
#pragma unroll
  for (int hf = 0; hf < NKT / 8; ++hf) {
    // pack P rows (4 consecutive keys per lane) into Pq[q][key_local], b64
#pragma unroll
    for (int qt = 0; qt < 2; ++qt)
#pragma unroll
      for (int tl = 0; tl < 8; ++tl) {
        int tn = hf * 8 + tl;
        bf16x4 pk;
#pragma unroll
        for (int r = 0; r < 4; ++r) pk[r] = (bf16)sacc[tn][qt][r];
        *(bf16x4*)(Pq + (qloc + qt * 16 + l16) * 136 + tl * 16 + qd * 4) = pk;
      }
    if (hf == 0) __syncthreads();   // Vt ready; Pq needs no cross-wave sync
#pragma unroll
    for (int ks = 0; ks < 4; ++ks) {
      bf16x8 pf[2];
#pragma unroll
      for (int qt = 0; qt < 2; ++qt)
        pf[qt] = *(const bf16x8*)(Pq + (qloc + qt * 16 + l16) * 136 + ks * 32 + qd * 8);
#pragma unroll
      for (int te = 0; te < 4; ++te) {
        bf16x8 vf = *(const bf16x8*)(Vt + (te * 16 + l16) * VS + hf * 128 + ks * 32 + qd * 8);
#pragma unroll
        for (int qt = 0; qt < 2; ++qt)
          oacc[te][qt] = __builtin_amdgcn_mfma_f32_16x16x32_bf16(vf, pf[qt], oacc[te][qt], 0, 0, 0);
      }
    }
  }

  // ---- store O^T: lane holds rows e=te*16+qd*4..+3, col q -> b64 stores ----
#pragma unroll
  for (int te = 0; te < 4; ++te)
#pragma unroll
    for (int qt = 0; qt < 2; ++qt) {
      int q = q0 + qloc + qt * 16 + l16;
      bf16x4 pk;
#pragma unroll
      for (int r = 0; r < 4; ++r) pk[r] = (bf16)oacc[te][qt][r];
      *(bf16x4*)(outp + (size_t)(rowbase + q * rstride) * 512 + h * 64 + te * 16 + qd * 4) = pk;
    }
}

extern "C" void kernel_launch(void* const* d_in, const int* in_sizes, int n_in,
                              void* d_out, int out_size, void* d_ws, size_t ws_size,
                              hipStream_t stream)
{
  (void)in_sizes; (void)n_in; (void)out_size; (void)ws_size;
  const float* x   = (const float*)d_in[0];   // [B,F,P,512] fp32
  const float* Wf  = (const float*)d_in[1];   // [3,8,64,512] fp32
  const float* bfb = (const float*)d_in[2];   // [1536] fp32
  const float* Wp  = (const float*)d_in[3];   // [3,8,64,8,64] fp32
  const float* bpb = (const float*)d_in[4];   // [1536] fp32
  const float* Wo  = (const float*)d_in[5];   // [8,64,512] fp32
  const float* bob = (const float*)d_in[6];   // [512] fp32
  float* out = (float*)d_out;                 // fp32 output

  char* ws = (char*)d_ws;
  bf16* qkv = (bf16*)ws;                                   // 65536x1536 (reused)
  bf16* fa  = (bf16*)(ws + (size_t)NROWS * 1536 * 2);      // 65536x512 (xb/fa/pa)
  bf16* xb  = fa;
  char* wbase = ws + (size_t)NROWS * 1536 * 2 + (size_t)NROWS * 512 * 2;
  bf16* wfb = (bf16*)wbase;
  bf16* wpb = (bf16*)(wbase + 1536 * 512 * 2);
  bf16* wot = (bf16*)(wbase + 2 * 1536 * 512 * 2);

  cvt_f32_bf16<<<(NROWS * 512) / (256 * 8), 256, 0, stream>>>(x, xb, NROWS * 512);
  cvt_f32_bf16<<<(1536 * 512) / (256 * 8), 256, 0, stream>>>(Wf, wfb, 1536 * 512);
  cvt_f32_bf16<<<(1536 * 512) / (256 * 8), 256, 0, stream>>>(Wp, wpb, 1536 * 512);
  transpose_wo<<<1024, 256, 0, stream>>>(Wo, wot);

  // 1) frame QKV  (M=65536, N=1536 -> 256x12 tiles)
  gemm_mn<bf16, 12><<<3072, 512, 0, stream>>>(xb, wfb, bfb, qkv);
  // 2) frame attention (keys = 128 frames)
  attn2<8, 0, 136><<<4096, 256, 0, stream>>>(qkv, fa);
  // 3) point QKV
  gemm_mn<bf16, 12><<<3072, 512, 0, stream>>>(fa, wpb, bpb, qkv);
  // 4) point attention (keys = 256 points)
  attn2<16, 1, 272><<<4096, 256, 0, stream>>>(qkv, fa);
  // 5) out projection (fp32 out, N=512 -> 256x4 tiles)
  gemm_mn<float, 4><<<1024, 512, 0, stream>>>(fa, wot, bob, out);
}

// Round 5
// 705.127 us; speedup vs baseline: 1.4669x; 1.4669x over previous
//
#include <hip/hip_runtime.h>
#include <hip/hip_bf16.h>
#include <stdint.h>

typedef __bf16 bf16;
typedef __attribute__((ext_vector_type(8))) __bf16 bf16x8;
typedef __attribute__((ext_vector_type(4))) __bf16 bf16x4;
typedef __attribute__((ext_vector_type(4))) float f32x4;

#define B_ 2
#define F_ 128
#define P_ 256
#define H_ 8
#define D_ 64
#define DIM_ 512
#define NROWS (B_*F_*P_)   // 65536

// async global->LDS, 16B per lane. LDS dest must be wave-uniform base + lane*16.
__device__ __forceinline__ void load_lds16(const void* g, void* l) {
  __builtin_amdgcn_global_load_lds(
      (__attribute__((address_space(1))) void*)(uintptr_t)g,
      (__attribute__((address_space(3))) void*)(uint32_t)(uintptr_t)l,
      16, 0, 0);
}

// fp32 -> bf16 cast, 8 elements/thread (n must be a multiple of 8)
__global__ void cvt_f32_bf16(const float* __restrict__ src, bf16* __restrict__ dst, int n)
{
  int i = (blockIdx.x * 256 + threadIdx.x) * 8;
  if (i < n) {
    float4 a = *(const float4*)(src + i);
    float4 b = *(const float4*)(src + i + 4);
    bf16x8 o;
    o[0] = (bf16)a.x; o[1] = (bf16)a.y; o[2] = (bf16)a.z; o[3] = (bf16)a.w;
    o[4] = (bf16)b.x; o[5] = (bf16)b.y; o[6] = (bf16)b.z; o[7] = (bf16)b.w;
    *(bf16x8*)(dst + i) = o;
  }
}

// W_o fp32 [512(he)][512(d)] -> wot bf16 [512(d)][512(he)]
__global__ void transpose_wo(const float* __restrict__ src, bf16* __restrict__ dst)
{
  int idx = blockIdx.x * 256 + threadIdx.x;
  int d = idx & 511, he = idx >> 9;
  dst[(size_t)d * 512 + he] = (bf16)src[(size_t)he * 512 + d];
}

// ---------------------------------------------------------------------------
// gemm256 (REVERTED to round-1 version, best measured: 143.6 us, MfmaUtil 30%,
// 0 bank conflicts). 256x256 tile, BK=32, 8 waves (2Mx4N), 512 thr, 128 KiB
// LDS 4-buffer ring, depth-3 counted vmcnt, k-octet swizzle g(row)=(row>>1)&3.
// Round-4's B-from-global regressed 2x (scattered L2 txns + L2 eviction by the
// C-write stream) — B stays in LDS.
// ---------------------------------------------------------------------------
template <typename OutT, int NT>
__global__ __launch_bounds__(512, 2)
void gemm256(const bf16* __restrict__ A, const bf16* __restrict__ Bt,
             const float* __restrict__ bias, OutT* __restrict__ C)
{
  constexpr int K = 512;
  constexpr int N = NT * 256;
  constexpr int NTILES = 16;              // K / 32
  __shared__ __align__(16) bf16 As[4][256 * 32];
  __shared__ __align__(16) bf16 Bs[4][256 * 32];

  const int t    = threadIdx.x;
  const int lane = t & 63;
  const int l16  = lane & 15;
  const int qd   = lane >> 4;
  const int wave = t >> 6;
  const int wm   = wave >> 2;             // 0..1  (M half)
  const int wn   = wave & 3;              // 0..3  (N quarter)

  constexpr int NWG = NT * 256;
  const int logical = (blockIdx.x & 7) * (NWG / 8) + (blockIdx.x >> 3);
  const int mBase = (logical / NT) * 256;
  const int nBase = (logical % NT) * 256;

  const int srow = t >> 2;
  const int soct = (((t & 3) ^ ((srow >> 1) & 3)) << 3);
  const bf16* aS0 = A  + (size_t)(mBase + srow)       * K + soct;
  const bf16* aS1 = A  + (size_t)(mBase + srow + 128) * K + soct;
  const bf16* bS0 = Bt + (size_t)(nBase + srow)       * K + soct;
  const bf16* bS1 = Bt + (size_t)(nBase + srow + 128) * K + soct;
  const int dst = t * 8;

#define STAGE_A(tt) do { \
    load_lds16(aS0 + (tt) * 32, &As[(tt) & 3][dst]); \
    load_lds16(aS1 + (tt) * 32, &As[(tt) & 3][4096 + dst]); } while (0)
#define STAGE_B(tt) do { \
    load_lds16(bS0 + (tt) * 32, &Bs[(tt) & 3][dst]); \
    load_lds16(bS1 + (tt) * 32, &Bs[(tt) & 3][4096 + dst]); } while (0)

  const int swz = ((qd ^ ((l16 >> 1) & 3)) << 3);
  const bf16* aRd = &As[0][(wm * 128 + l16) * 32 + swz];
  const bf16* bRd = &Bs[0][(wn * 64  + l16) * 32 + swz];

  f32x4 acc[8][4] = {};

  STAGE_A(0); STAGE_B(0); STAGE_A(1); STAGE_B(1); STAGE_A(2); STAGE_B(2);

#define MF(i, j, av, bv) \
  acc[i][j] = __builtin_amdgcn_mfma_f32_16x16x32_bf16(av, bv, acc[i][j], 0, 0, 0)

#pragma unroll
  for (int tt = 0; tt < NTILES; ++tt) {
    if (tt + 3 < NTILES) STAGE_A(tt + 3);
    if      (tt <= NTILES - 4) asm volatile("s_waitcnt vmcnt(10)" ::: "memory");
    else if (tt == NTILES - 3) asm volatile("s_waitcnt vmcnt(8)"  ::: "memory");
    else if (tt == NTILES - 2) asm volatile("s_waitcnt vmcnt(4)"  ::: "memory");
    else                       asm volatile("s_waitcnt vmcnt(0)"  ::: "memory");
    __builtin_amdgcn_s_barrier();
    asm volatile("" ::: "memory");

    const bf16* aB = aRd + (tt & 3) * (256 * 32);
    const bf16* bB = bRd + (tt & 3) * (256 * 32);

    bf16x8 a[4], b[4];
#pragma unroll
    for (int j = 0; j < 4; ++j) b[j] = *(const bf16x8*)(bB + j * 512);
#pragma unroll
    for (int i = 0; i < 4; ++i) a[i] = *(const bf16x8*)(aB + i * 512);
    __builtin_amdgcn_s_setprio(1);
#pragma unroll
    for (int i = 0; i < 4; ++i)
#pragma unroll
      for (int j = 0; j < 4; ++j) MF(i, j, a[i], b[j]);
    __builtin_amdgcn_s_setprio(0);
    __builtin_amdgcn_s_barrier();
    asm volatile("" ::: "memory");

    if (tt + 3 < NTILES) STAGE_B(tt + 3);
#pragma unroll
    for (int i = 0; i < 4; ++i) a[i] = *(const bf16x8*)(aB + (4 + i) * 512);
    __builtin_amdgcn_s_setprio(1);
#pragma unroll
    for (int i = 0; i < 4; ++i)
#pragma unroll
      for (int j = 0; j < 4; ++j) MF(4 + i, j, a[i], b[j]);
    __builtin_amdgcn_s_setprio(0);
    __builtin_amdgcn_s_barrier();
    asm volatile("" ::: "memory");
  }
#undef STAGE_A
#undef STAGE_B
#undef MF

#pragma unroll
  for (int j = 0; j < 4; ++j) {
    const int coln = nBase + wn * 64 + j * 16 + l16;
    const float bv = bias[coln];
#pragma unroll
    for (int i = 0; i < 8; ++i) {
      const int rowm = mBase + wm * 128 + i * 16 + qd * 4;
#pragma unroll
      for (int r = 0; r < 4; ++r)
        C[(size_t)(rowm + r) * N + coln] = (OutT)(acc[i][j][r] + bv);
    }
  }
}

// ---------------------------------------------------------------------------
// Attention v3. Same verified math as v2 (S^T = K.Q^T, reg softmax,
// O^T = V^T.P^T via Pq round-trip); data movement rewritten:
//  - K staged into LDS via global_load_lds (4 insts/thread, linear dest),
//    oct-XOR swizzle slot = oct ^ (key&7) pre-applied on the per-lane global
//    source; QK^T reads K from LDS conflict-free (was: 16 scattered global
//    b128 inside the MFMA chain, ~16x 64B txns each, 786KB row stride).
//  - V loads issued at kernel start into regs; the transpose ds_writes are
//    DEFERRED until after QK^T (T14 split: HBM latency hides under QK^T,
//    DS writes overlap softmax). hf==0 barrier publishes Vt as before.
//  - counted gate: [K stages x4][V x4, Q x4] -> vmcnt(8) + barrier (K ready,
//    V/Q still in flight; compiler adds its own wait before first MFMA use).
//  - MODE1 (point): ONE 512-thread block per (b,f,h) — 8 waves share one K/V
//    staging (halves K/V global traffic vs two q-half blocks). 136 KB LDS.
// ---------------------------------------------------------------------------
template <int NKT, int MODE, int VS>
__global__ __launch_bounds__(MODE ? 512 : 256, 2)
void attn3(const bf16* __restrict__ qkv, bf16* __restrict__ outp)
{
  constexpr int TB   = MODE ? 512 : 256;   // threads (4 or 8 waves)
  constexpr int KEYS = NKT * 16;

  __shared__ __align__(16) bf16 K_lds[KEYS * 64];
  __shared__ __align__(16) bf16 Vt[64 * VS];
  __shared__ __align__(16) bf16 Pq[(TB / 2) * 136];

  const int t    = threadIdx.x;
  const int lane = t & 63;
  const int wave = t >> 6;
  const int l16  = lane & 15;
  const int qd   = lane >> 4;

  const int bid = blockIdx.x;
  int h, rowbase, rstride;
  if (MODE == 0) {
    h = bid & 7;
    int p = (bid >> 3) & (P_ - 1);
    int b = bid >> 11;
    rowbase = b * F_ * P_ + p; rstride = P_;
  } else {
    h = bid & 7;
    int f = (bid >> 3) & (F_ - 1);
    int b = bid >> 10;
    rowbase = (b * F_ + f) * P_; rstride = 1;
  }

  // ---- 1) K staging: global_load_lds, linear dest, source pre-swizzled ----
  // chunk gi covers LDS elems gi*8..+7 = row key=gi>>3, slot gi&7; logical
  // k-octet o = slot ^ (key&7)  (involution; reader applies the same XOR).
  constexpr int KP = (KEYS * 8) / TB;      // 4 staging insts/thread
#pragma unroll
  for (int p = 0; p < KP; ++p) {
    int gi  = p * TB + t;
    int key = gi >> 3;
    int oct = (gi & 7) ^ (key & 7);
    load_lds16(qkv + (size_t)(rowbase + key * rstride) * 1536 + 512 + h * 64 + oct * 8,
               K_lds + gi * 8);
  }
  __builtin_amdgcn_sched_barrier(0);

  // ---- 2) V loads -> regs (writes deferred past QK^T); Q frags -> regs ----
  const int vkey = t >> 1;                 // TB/2 == KEYS: one pass
  const int eh   = (t & 1) * 32;
  const bf16* vsrc = qkv + (size_t)(rowbase + vkey * rstride) * 1536 + 1024 + h * 64 + eh;
  bf16x8 v[4];
#pragma unroll
  for (int jj = 0; jj < 4; ++jj) v[jj] = *(const bf16x8*)(vsrc + jj * 8);

  const int qloc = wave * 32;
  bf16x8 qf[2][2];
#pragma unroll
  for (int qt = 0; qt < 2; ++qt)
#pragma unroll
    for (int ks = 0; ks < 2; ++ks)
      qf[qt][ks] = *(const bf16x8*)(qkv +
          (size_t)(rowbase + (qloc + qt * 16 + l16) * rstride) * 1536 +
          h * 64 + ks * 32 + qd * 8);
  __builtin_amdgcn_sched_barrier(0);

  // gate: drain the 4 K-stages (newest 8 = V + Q stay in flight)
  asm volatile("s_waitcnt vmcnt(8)" ::: "memory");
  __builtin_amdgcn_s_barrier();            // all waves' K staged
  asm volatile("" ::: "memory");

  // ---- 3) S^T = K.Q^T : K fragments from LDS (conflict-free) ----
  f32x4 sacc[NKT][2] = {};
#pragma unroll
  for (int tn = 0; tn < NKT; ++tn) {
    int key = tn * 16 + l16;
    const bf16* kr = K_lds + key * 64;
    int s0 = ((qd ^ (key & 7)) << 3);
    bf16x8 kf0 = *(const bf16x8*)(kr + s0);
    bf16x8 kf1 = *(const bf16x8*)(kr + (s0 ^ 32));
#pragma unroll
    for (int qt = 0; qt < 2; ++qt) {
      sacc[tn][qt] = __builtin_amdgcn_mfma_f32_16x16x32_bf16(kf0, qf[qt][0], sacc[tn][qt], 0, 0, 0);
      sacc[tn][qt] = __builtin_amdgcn_mfma_f32_16x16x32_bf16(kf1, qf[qt][1], sacc[tn][qt], 0, 0, 0);
    }
  }

  // ---- 4) deferred V transpose into LDS (overlaps softmax below) ----
#pragma unroll
  for (int jj = 0; jj < 4; ++jj)
#pragma unroll
    for (int j = 0; j < 8; ++j)
      Vt[(eh + jj * 8 + j) * VS + vkey] = v[jj][j];

  // ---- 5) softmax over keys: in-lane (tn,r) + shfl over qd ----
#pragma unroll
  for (int qt = 0; qt < 2; ++qt) {
    float m = -3.0e38f;
#pragma unroll
    for (int tn = 0; tn < NKT; ++tn)
#pragma unroll
      for (int r = 0; r < 4; ++r) m = fmaxf(m, sacc[tn][qt][r]);
    m = fmaxf(m, __shfl_xor(m, 16));
    m = fmaxf(m, __shfl_xor(m, 32));
    float s = 0.0f;
#pragma unroll
    for (int tn = 0; tn < NKT; ++tn)
#pragma unroll
      for (int r = 0; r < 4; ++r) {
        float e0 = __expf(sacc[tn][qt][r] - m);
        sacc[tn][qt][r] = e0;
        s += e0;
      }
    s += __shfl_xor(s, 16);
    s += __shfl_xor(s, 32);
    float inv = 1.0f / s;
#pragma unroll
    for (int tn = 0; tn < NKT; ++tn)
#pragma unroll
      for (int r = 0; r < 4; ++r) sacc[tn][qt][r] *= inv;
  }

  // ---- 6) O^T = V^T.P^T, key-halves of 128; Pq rows are wave-private ----
  f32x4 oacc[4][2] = {};
#pragma unroll
  for (int hf = 0; hf < NKT / 8; ++hf) {
#pragma unroll
    for (int qt = 0; qt < 2; ++qt)
#pragma unroll
      for (int tl = 0; tl < 8; ++tl) {
        int tn = hf * 8 + tl;
        bf16x4 pk;
#pragma unroll
        for (int r = 0; r < 4; ++r) pk[r] = (bf16)sacc[tn][qt][r];
        *(bf16x4*)(Pq + (qloc + qt * 16 + l16) * 136 + tl * 16 + qd * 4) = pk;
      }
    if (hf == 0) __syncthreads();   // Vt (all waves) + own Pq ready
#pragma unroll
    for (int ks = 0; ks < 4; ++ks) {
      bf16x8 pf[2];
#pragma unroll
      for (int qt = 0; qt < 2; ++qt)
        pf[qt] = *(const bf16x8*)(Pq + (qloc + qt * 16 + l16) * 136 + ks * 32 + qd * 8);
#pragma unroll
      for (int te = 0; te < 4; ++te) {
        bf16x8 vf = *(const bf16x8*)(Vt + (te * 16 + l16) * VS + hf * 128 + ks * 32 + qd * 8);
#pragma unroll
        for (int qt = 0; qt < 2; ++qt)
          oacc[te][qt] = __builtin_amdgcn_mfma_f32_16x16x32_bf16(vf, pf[qt], oacc[te][qt], 0, 0, 0);
      }
    }
  }

  // ---- 7) store O^T: lane holds rows e=te*16+qd*4..+3, col q ----
#pragma unroll
  for (int te = 0; te < 4; ++te)
#pragma unroll
    for (int qt = 0; qt < 2; ++qt) {
      int q = qloc + qt * 16 + l16;
      bf16x4 pk;
#pragma unroll
      for (int r = 0; r < 4; ++r) pk[r] = (bf16)oacc[te][qt][r];
      *(bf16x4*)(outp + (size_t)(rowbase + q * rstride) * 512 + h * 64 + te * 16 + qd * 4) = pk;
    }
}

extern "C" void kernel_launch(void* const* d_in, const int* in_sizes, int n_in,
                              void* d_out, int out_size, void* d_ws, size_t ws_size,
                              hipStream_t stream)
{
  (void)in_sizes; (void)n_in; (void)out_size; (void)ws_size;
  const float* x   = (const float*)d_in[0];   // [B,F,P,512] fp32
  const float* Wf  = (const float*)d_in[1];   // [3,8,64,512] fp32
  const float* bfb = (const float*)d_in[2];   // [1536] fp32
  const float* Wp  = (const float*)d_in[3];   // [3,8,64,8,64] fp32
  const float* bpb = (const float*)d_in[4];   // [1536] fp32
  const float* Wo  = (const float*)d_in[5];   // [8,64,512] fp32
  const float* bob = (const float*)d_in[6];   // [512] fp32
  float* out = (float*)d_out;                 // fp32 output

  char* ws = (char*)d_ws;
  bf16* qkv = (bf16*)ws;                                   // 65536x1536 (reused)
  bf16* fa  = (bf16*)(ws + (size_t)NROWS * 1536 * 2);      // 65536x512 (xb/fa/pa)
  bf16* xb  = fa;
  char* wbase = ws + (size_t)NROWS * 1536 * 2 + (size_t)NROWS * 512 * 2;
  bf16* wfb = (bf16*)wbase;
  bf16* wpb = (bf16*)(wbase + 1536 * 512 * 2);
  bf16* wot = (bf16*)(wbase + 2 * 1536 * 512 * 2);

  cvt_f32_bf16<<<(NROWS * 512) / (256 * 8), 256, 0, stream>>>(x, xb, NROWS * 512);
  cvt_f32_bf16<<<(1536 * 512) / (256 * 8), 256, 0, stream>>>(Wf, wfb, 1536 * 512);
  cvt_f32_bf16<<<(1536 * 512) / (256 * 8), 256, 0, stream>>>(Wp, wpb, 1536 * 512);
  transpose_wo<<<1024, 256, 0, stream>>>(Wo, wot);

  // 1) frame QKV
  gemm256<bf16, 6><<<1536, 512, 0, stream>>>(xb, wfb, bfb, qkv);
  // 2) frame attention (keys = 128 frames), 4 waves/block, 2 blocks/CU
  attn3<8, 0, 136><<<4096, 256, 0, stream>>>(qkv, fa);
  // 3) point QKV
  gemm256<bf16, 6><<<1536, 512, 0, stream>>>(fa, wpb, bpb, qkv);
  // 4) point attention (keys = 256 points), 8 waves/block share K/V staging
  attn3<16, 1, 272><<<2048, 512, 0, stream>>>(qkv, fa);
  // 5) out projection (fp32 out)
  gemm256<float, 2><<<512, 512, 0, stream>>>(fa, wot, bob, out);
}